// Round 3
// baseline (1088.079 us; speedup 1.0000x reference)
//
#include <hip/hip_runtime.h>
#include <float.h>
#include <math.h>

#define BB   2
#define NPTS 2048
#define NODES (BB*NPTS)   // 4096
#define NNB  32
#define NH   4
#define NDH  64

// ======================= KNN (exact numpy replication) =======================
__global__ __launch_bounds__(256) void knn_kernel(const float* __restrict__ coors,
    int* __restrict__ idx_out, float* __restrict__ dnb_out, float* __restrict__ rel_out) {
#pragma clang fp contract(off)
  const int node = blockIdx.x;
  const int b = node >> 11;
  const int i = node & (NPTS - 1);
  __shared__ float cx[NPTS], cy[NPTS], cz[NPTS];
  __shared__ float wdist[4]; __shared__ int wjj[4];
  __shared__ float win_d_s; __shared__ int win_j_s;
  __shared__ float sel_d[NNB]; __shared__ int sel_j[NNB];
  const float* cb = coors + (size_t)b * NPTS * 3;
  for (int j = threadIdx.x; j < NPTS; j += 256) {
    cx[j] = cb[3*j]; cy[j] = cb[3*j+1]; cz[j] = cb[3*j+2];
  }
  __syncthreads();
  const float xi = cx[i], yi = cy[i], zi = cz[i];
  float dl[8]; int jl[8];
  #pragma unroll
  for (int s = 0; s < 8; ++s) {
    int j = threadIdx.x + (s << 8);
    float dx = xi - cx[j];
    float dy = yi - cy[j];
    float dz = zi - cz[j];
    float ss = dx*dx + dy*dy;   // contract(off): matches numpy rounding
    ss = ss + dz*dz;
    dl[s] = sqrtf(ss);          // correctly rounded by default on HIP
    jl[s] = j;
  }
  for (int it = 0; it < NNB; ++it) {
    float bd = FLT_MAX; int bj = 0x7FFFFFFF;
    #pragma unroll
    for (int s = 0; s < 8; ++s)
      if (dl[s] < bd || (dl[s] == bd && jl[s] < bj)) { bd = dl[s]; bj = jl[s]; }
    #pragma unroll
    for (int off = 32; off > 0; off >>= 1) {
      float od = __shfl_down(bd, off, 64);
      int   oj = __shfl_down(bj, off, 64);
      if (od < bd || (od == bd && oj < bj)) { bd = od; bj = oj; }
    }
    if ((threadIdx.x & 63) == 0) { wdist[threadIdx.x >> 6] = bd; wjj[threadIdx.x >> 6] = bj; }
    __syncthreads();
    if (threadIdx.x == 0) {
      float fd = wdist[0]; int fj = wjj[0];
      #pragma unroll
      for (int w = 1; w < 4; ++w)
        if (wdist[w] < fd || (wdist[w] == fd && wjj[w] < fj)) { fd = wdist[w]; fj = wjj[w]; }
      win_d_s = fd; win_j_s = fj; sel_d[it] = fd; sel_j[it] = fj;
    }
    __syncthreads();
    const int wj = win_j_s;
    #pragma unroll
    for (int s = 0; s < 8; ++s) if (jl[s] == wj) dl[s] = FLT_MAX;
    __syncthreads();
  }
  if (threadIdx.x < NNB) {
    int s = threadIdx.x;
    int j = sel_j[s];
    idx_out[(size_t)node*NNB + s] = j;
    dnb_out[(size_t)node*NNB + s] = sel_d[s];
    float* rp = rel_out + ((size_t)node*NNB + s)*3;
    rp[0] = xi - cx[j]; rp[1] = yi - cy[j]; rp[2] = zi - cz[j];
  }
}

// ======================= generic f32 GEMM (64x64 tile) =======================
// C[M,N] = A[M,K] @ B[K,N] (+bias). SPLIT: scatter 768 cols into 3x256 (q,k,v).
template<bool SPLIT>
__global__ __launch_bounds__(256) void gemm_kernel(const float* __restrict__ A,
    const float* __restrict__ Bm, const float* __restrict__ bias,
    float* __restrict__ C0, float* __restrict__ C1, float* __restrict__ C2,
    int Mn, int Nn, int Kn, int lda, int ldb) {
  __shared__ float As[64][17];
  __shared__ __align__(16) float Bs[16][64];
  const int bm = blockIdx.x * 64, bn = blockIdx.y * 64;
  const int tx = threadIdx.x & 15, ty = threadIdx.x >> 4;
  const int lm = threadIdx.x >> 2, lk = (threadIdx.x & 3) * 4;
  const int br = threadIdx.x >> 4, bc = (threadIdx.x & 15) * 4;
  float acc[4][4] = {};
  for (int k0 = 0; k0 < Kn; k0 += 16) {
    float4 av = *(const float4*)(A + (size_t)(bm + lm)*lda + k0 + lk);
    As[lm][lk+0] = av.x; As[lm][lk+1] = av.y; As[lm][lk+2] = av.z; As[lm][lk+3] = av.w;
    float4 bv = *(const float4*)(Bm + (size_t)(k0 + br)*ldb + bn + bc);
    *(float4*)&Bs[br][bc] = bv;
    __syncthreads();
    #pragma unroll
    for (int kk = 0; kk < 16; ++kk) {
      float a0 = As[ty*4+0][kk], a1 = As[ty*4+1][kk], a2 = As[ty*4+2][kk], a3 = As[ty*4+3][kk];
      float4 bq = *(const float4*)&Bs[kk][tx*4];
      acc[0][0] += a0*bq.x; acc[0][1] += a0*bq.y; acc[0][2] += a0*bq.z; acc[0][3] += a0*bq.w;
      acc[1][0] += a1*bq.x; acc[1][1] += a1*bq.y; acc[1][2] += a1*bq.z; acc[1][3] += a1*bq.w;
      acc[2][0] += a2*bq.x; acc[2][1] += a2*bq.y; acc[2][2] += a2*bq.z; acc[2][3] += a2*bq.w;
      acc[3][0] += a3*bq.x; acc[3][1] += a3*bq.y; acc[3][2] += a3*bq.z; acc[3][3] += a3*bq.w;
    }
    __syncthreads();
  }
  #pragma unroll
  for (int r = 0; r < 4; ++r) {
    #pragma unroll
    for (int c = 0; c < 4; ++c) {
      int row = bm + ty*4 + r, col = bn + tx*4 + c;
      float vv = acc[r][c];
      if (bias) vv += bias[col];
      if (SPLIT) {
        int w = col >> 8, cc = col & 255;
        float* Cp = (w == 0) ? C0 : ((w == 1) ? C1 : C2);
        Cp[(size_t)row*256 + cc] = vv;
      } else {
        C0[(size_t)row*Nn + col] = vv;
      }
    }
  }
}

// ======================= fused per-node kernel =======================
// block = one node (b,i), 512 threads, dynamic LDS.
__global__ __launch_bounds__(512) void fused_kernel(
    const int* __restrict__ idx, const float* __restrict__ dnb, const float* __restrict__ relnb,
    const float* __restrict__ qe, const float* __restrict__ ke, const float* __restrict__ v,
    const float* __restrict__ w_p1, const float* __restrict__ b_p1,
    const float* __restrict__ w_p2, const float* __restrict__ b_p2,
    const float* __restrict__ w_e1, const float* __restrict__ w_e2, const float* __restrict__ b_e2,
    const float* __restrict__ w_a1, const float* __restrict__ b_a1,
    const float* __restrict__ w_a2, const float* __restrict__ b_a2,
    const float* __restrict__ w_c1, const float* __restrict__ b_c1,
    const float* __restrict__ w_c2, const float* __restrict__ b_c2,
    float* __restrict__ hsum, float* __restrict__ coors_out) {
  extern __shared__ float sm[];
  float* w_p1s = sm;             // 1152
  float* b_p1s = w_p1s + 1152;   // 128
  float* w_p2s = b_p1s + 128;    // 8192
  float* b_p2s = w_p2s + 8192;   // 64
  float* w_e1s = b_p2s + 64;     // 8192
  float* w_e2s = w_e1s + 8192;   // 2048
  float* b_e2s = w_e2s + 2048;   // 16
  float* w_a1s = b_e2s + 16;     // 1024
  float* b_a1s = w_a1s + 1024;   // 64
  float* w_a2s = b_a1s + 64;     // 64
  float* w_c1s = w_a2s + 64;     // 4096
  float* b_c1s = w_c1s + 4096;   // 64
  float* w_c2s = b_c1s + 64;     // 64
  float* qe_s  = w_c2s + 64;     // 512
  float* fe_s  = qe_s + 512;     // 288
  float* pos_s = fe_s + 288;     // 2048  (32 x 64)
  float* pose_s= pos_s + 2048;   // 4096  (32 x 128)
  float* scr   = pose_s + 4096;  // 4096  (ph / h1e / ch)
  float* m_all = scr + 4096;     // 2048  (j, h*16+m)  == coor_in layout
  float* sim_s = m_all + 2048;   // 128   (h,j)
  float* attn_s= sim_s + 128;    // 128
  float* part_s= attn_s + 128;   // 512
  float* cw_s  = part_s + 512;   // 32
  float* dnb_s = cw_s + 32;      // 32
  float* rel_s = dnb_s + 32;     // 96
  int*   idx_s = (int*)(rel_s + 96); // 32
  const int t = threadIdx.x;
  const int node = blockIdx.x;
  const int b = node >> 11;

  // ---- stage weights + per-node data ----
  for (int i = t; i < 1152; i += 512) w_p1s[i] = w_p1[i];
  for (int i = t; i < 8192; i += 512) w_p2s[i] = w_p2[i];
  for (int i = t; i < 8192; i += 512) w_e1s[i] = w_e1[i];
  for (int i = t; i < 2048; i += 512) w_e2s[i] = w_e2[i];
  for (int i = t; i < 4096; i += 512) w_c1s[i] = w_c1[i];
  for (int i = t; i < 1024; i += 512) w_a1s[i] = w_a1[i];
  if (t < 128) b_p1s[t] = b_p1[t];
  if (t >= 128 && t < 192) b_p2s[t-128] = b_p2[t-128];
  if (t >= 192 && t < 208) b_e2s[t-192] = b_e2[t-192];
  if (t >= 256 && t < 320) b_a1s[t-256] = b_a1[t-256];
  if (t >= 320 && t < 384) w_a2s[t-320] = w_a2[t-320];
  if (t >= 384 && t < 448) b_c1s[t-384] = b_c1[t-384];
  if (t >= 448 && t < 512) w_c2s[t-448] = w_c2[t-448];
  qe_s[t] = qe[(size_t)node*512 + t];
  if (t < NNB) { idx_s[t] = idx[(size_t)node*NNB + t]; dnb_s[t] = dnb[(size_t)node*NNB + t]; }
  if (t < NNB*3) rel_s[t] = relnb[(size_t)node*NNB*3 + t];
  __syncthreads();

  // ---- P1a: fourier features fe[32][9] ----
  if (t < NNB) {
    float d = dnb_s[t];
    float* f = fe_s + t*9;
    f[0] = sinf(d);          f[1] = sinf(d*0.5f);
    f[2] = sinf(d*0.25f);    f[3] = sinf(d*0.125f);
    f[4] = cosf(d);          f[5] = cosf(d*0.5f);
    f[6] = cosf(d*0.25f);    f[7] = cosf(d*0.125f);
    f[8] = d;
  }
  __syncthreads();

  // ---- P1b: ph = relu(fe @ w_p1 + b_p1) -> scr[j*128+o] ----
  #pragma unroll
  for (int rep = 0; rep < 8; ++rep) {
    int i2 = t + rep*512;
    int j = i2 >> 7, o = i2 & 127;
    const float* f = fe_s + j*9;
    float acc = b_p1s[o];
    #pragma unroll
    for (int r = 0; r < 9; ++r) acc += f[r] * w_p1s[r*128 + o];
    scr[i2] = fmaxf(acc, 0.0f);
  }
  __syncthreads();

  // ---- P1c: pos = ph @ w_p2 + b_p2 -> pos_s[j*64+oo] (thread: 1 j x 4 cols) ----
  {
    int j = t >> 4, og = (t & 15) * 4;
    const float* ph = scr + j*128;
    float s0=0,s1=0,s2=0,s3=0, u0=0,u1=0,u2=0,u3=0;
    #pragma unroll 8
    for (int kx = 0; kx < 128; kx += 2) {
      float p0 = ph[kx], p1 = ph[kx+1];
      float4 w0 = *(const float4*)(w_p2s + kx*64 + og);
      float4 w1 = *(const float4*)(w_p2s + (kx+1)*64 + og);
      s0 += p0*w0.x; s1 += p0*w0.y; s2 += p0*w0.z; s3 += p0*w0.w;
      u0 += p1*w1.x; u1 += p1*w1.y; u2 += p1*w1.z; u3 += p1*w1.w;
    }
    pos_s[j*64+og+0] = b_p2s[og+0] + (s0+u0);
    pos_s[j*64+og+1] = b_p2s[og+1] + (s1+u1);
    pos_s[j*64+og+2] = b_p2s[og+2] + (s2+u2);
    pos_s[j*64+og+3] = b_p2s[og+3] + (s3+u3);
  }
  __syncthreads();

  // ---- P2: pose = pos @ w_e1 -> pose_s[j*128+o] (thread: 1 j x 4 cols, 2 reps) ----
  #pragma unroll
  for (int rep = 0; rep < 2; ++rep) {
    int i2 = t + rep*512;
    int j = i2 >> 5, og = (i2 & 31) * 4;
    const float* pj = pos_s + j*64;
    float s0=0,s1=0,s2=0,s3=0, u0=0,u1=0,u2=0,u3=0;
    #pragma unroll 8
    for (int kx = 0; kx < 64; kx += 2) {
      float p0 = pj[kx], p1 = pj[kx+1];
      float4 w0 = *(const float4*)(w_e1s + kx*128 + og);
      float4 w1 = *(const float4*)(w_e1s + (kx+1)*128 + og);
      s0 += p0*w0.x; s1 += p0*w0.y; s2 += p0*w0.z; s3 += p0*w0.w;
      u0 += p1*w1.x; u1 += p1*w1.y; u2 += p1*w1.z; u3 += p1*w1.w;
    }
    pose_s[j*128+og+0] = s0+u0;
    pose_s[j*128+og+1] = s1+u1;
    pose_s[j*128+og+2] = s2+u2;
    pose_s[j*128+og+3] = s3+u3;
  }
  __syncthreads();

  // ---- P3: per head: h1e = relu(qe - ke + pose) ; m = relu(h1e @ w_e2 + b_e2) ----
  for (int h = 0; h < NH; ++h) {
    #pragma unroll
    for (int rep = 0; rep < 8; ++rep) {
      int i2 = t + rep*512;
      int j = i2 >> 7, o = i2 & 127;
      float kv = ke[((size_t)((b << 11) + idx_s[j])*NH + h)*128 + o];
      scr[i2] = fmaxf(qe_s[h*128+o] - kv + pose_s[i2], 0.0f);
    }
    __syncthreads();
    if (t < 128) {
      int j = t >> 2, mmg = (t & 3) * 4;
      const float* hp = scr + j*128;
      float s0=0,s1=0,s2=0,s3=0, u0=0,u1=0,u2=0,u3=0;
      #pragma unroll 8
      for (int kx = 0; kx < 128; kx += 2) {
        float h0 = hp[kx], h1 = hp[kx+1];
        float4 w0 = *(const float4*)(w_e2s + kx*16 + mmg);
        float4 w1 = *(const float4*)(w_e2s + (kx+1)*16 + mmg);
        s0 += h0*w0.x; s1 += h0*w0.y; s2 += h0*w0.z; s3 += h0*w0.w;
        u0 += h1*w1.x; u1 += h1*w1.y; u2 += h1*w1.z; u3 += h1*w1.w;
      }
      float* mp = m_all + j*64 + h*16 + mmg;
      mp[0] = fmaxf(b_e2s[mmg+0] + (s0+u0), 0.0f);
      mp[1] = fmaxf(b_e2s[mmg+1] + (s1+u1), 0.0f);
      mp[2] = fmaxf(b_e2s[mmg+2] + (s2+u2), 0.0f);
      mp[3] = fmaxf(b_e2s[mmg+3] + (s3+u3), 0.0f);
    }
    __syncthreads();
  }

  // ---- P4a: sim = relu(m @ w_a1 + b_a1) @ w_a2 + b_a2 (thread: (j,h,quarter)) ----
  {
    int j = t >> 4, h = (t >> 2) & 3, qq = t & 3;
    float mreg[16];
    #pragma unroll
    for (int mt = 0; mt < 16; ++mt) mreg[mt] = m_all[j*64 + h*16 + mt];
    float acc = 0.0f;
    #pragma unroll
    for (int oi = 0; oi < 16; ++oi) {
      int oo = qq*16 + oi;
      float ah = b_a1s[oo];
      #pragma unroll
      for (int mt = 0; mt < 16; ++mt) ah += mreg[mt] * w_a1s[mt*64 + oo];
      acc += fmaxf(ah, 0.0f) * w_a2s[oo];
    }
    part_s[t] = acc;
  }
  __syncthreads();
  if (t < 128) {
    int j = t >> 2, h = t & 3;
    const float* pp = part_s + j*16 + h*4;
    sim_s[h*32 + j] = ((pp[0]+pp[1]) + (pp[2]+pp[3])) + b_a2[0];
  }
  __syncthreads();
  if (t < 4) {   // softmax over j, faithful to reference
    const float* sp = sim_s + t*32;
    float mx = sp[0];
    for (int j = 1; j < 32; ++j) mx = fmaxf(mx, sp[j]);
    float s = 0.0f; float* ap = attn_s + t*32;
    for (int j = 0; j < 32; ++j) { float e = expf(sp[j] - mx); ap[j] = e; s += e; }
    for (int j = 0; j < 32; ++j) ap[j] = ap[j] / s;
  }
  __syncthreads();

  // ---- P4b: coor MLP: ch = relu(m_all @ w_c1 + b_c1) -> scr ; cw ; coors_out ----
  {
    int j = t >> 4, og = (t & 15) * 4;
    const float* mj = m_all + j*64;
    float s0=0,s1=0,s2=0,s3=0, u0=0,u1=0,u2=0,u3=0;
    #pragma unroll 8
    for (int kx = 0; kx < 64; kx += 2) {
      float m0 = mj[kx], m1 = mj[kx+1];
      float4 w0 = *(const float4*)(w_c1s + kx*64 + og);
      float4 w1 = *(const float4*)(w_c1s + (kx+1)*64 + og);
      s0 += m0*w0.x; s1 += m0*w0.y; s2 += m0*w0.z; s3 += m0*w0.w;
      u0 += m1*w1.x; u1 += m1*w1.y; u2 += m1*w1.z; u3 += m1*w1.w;
    }
    scr[j*64+og+0] = fmaxf(b_c1s[og+0] + (s0+u0), 0.0f);
    scr[j*64+og+1] = fmaxf(b_c1s[og+1] + (s1+u1), 0.0f);
    scr[j*64+og+2] = fmaxf(b_c1s[og+2] + (s2+u2), 0.0f);
    scr[j*64+og+3] = fmaxf(b_c1s[og+3] + (s3+u3), 0.0f);
  }
  __syncthreads();
  if (t < 128) {
    int j = t >> 2, qq = t & 3;
    const float* cj = scr + j*64 + qq*16;
    const float* wc = w_c2s + qq*16;
    float acc = 0.0f;
    #pragma unroll
    for (int oo = 0; oo < 16; ++oo) acc += cj[oo] * wc[oo];
    part_s[t] = acc;
  }
  __syncthreads();
  if (t < 32) {
    const float* pp = part_s + t*4;
    cw_s[t] = ((pp[0]+pp[1]) + (pp[2]+pp[3])) + b_c2[0];
  }
  __syncthreads();
  if (t < 3) {
    float acc = 0.0f;
    for (int j = 0; j < 32; ++j) acc += cw_s[j] * rel_s[j*3 + t];
    coors_out[(size_t)node*3 + t] = acc;
  }

  // ---- P5: out_head = sum_j attn[h][j] * (v[idx_j] + pos[j]) ----
  if (t < 256) {
    int h = t >> 6, dd = t & 63;
    float acc = 0.0f;
    for (int j = 0; j < NNB; ++j) {
      float vv = v[(size_t)((b << 11) + idx_s[j])*256 + t] + pos_s[j*64 + dd];
      acc += attn_s[h*32 + j] * vv;
    }
    hsum[(size_t)node*256 + t] = acc;
  }
}

// ======================= launch =======================
extern "C" void kernel_launch(void* const* d_in, const int* in_sizes, int n_in,
                              void* d_out, int out_size, void* d_ws, size_t ws_size,
                              hipStream_t stream) {
  const float* feats = (const float*)d_in[0];
  const float* coors = (const float*)d_in[1];
  const float* w_qkv = (const float*)d_in[2];
  const float* w_out = (const float*)d_in[3];
  const float* b_out = (const float*)d_in[4];
  const float* w_p1  = (const float*)d_in[5];
  const float* b_p1  = (const float*)d_in[6];
  const float* w_p2  = (const float*)d_in[7];
  const float* b_p2  = (const float*)d_in[8];
  const float* w_e1  = (const float*)d_in[9];
  const float* b_e1  = (const float*)d_in[10];
  const float* w_e2  = (const float*)d_in[11];
  const float* b_e2  = (const float*)d_in[12];
  const float* w_a1  = (const float*)d_in[13];
  const float* b_a1  = (const float*)d_in[14];
  const float* w_a2  = (const float*)d_in[15];
  const float* b_a2  = (const float*)d_in[16];
  const float* w_c1  = (const float*)d_in[17];
  const float* b_c1  = (const float*)d_in[18];
  const float* w_c2  = (const float*)d_in[19];
  const float* b_c2  = (const float*)d_in[20];

  float* ws   = (float*)d_ws;
  float* q    = ws;                 // 4096*256
  float* k    = q   + 1048576;
  float* v    = k   + 1048576;
  float* qe   = v   + 1048576;      // 16384*128 (incl. +b_e1)
  float* ke   = qe  + 2097152;
  float* hsum = ke  + 2097152;      // 4096*256
  int*   idx  = (int*)(hsum + 1048576);   // 4096*32
  float* dnb  = (float*)(idx + 131072);
  float* reln = dnb + 131072;       // 4096*32*3

  float* outF = (float*)d_out;              // (B,N,256)
  float* outC = outF + (size_t)NODES*256;   // (B,N,3)

  knn_kernel<<<dim3(NODES), dim3(256), 0, stream>>>(coors, idx, dnb, reln);

  gemm_kernel<true><<<dim3(64, 12), dim3(256), 0, stream>>>(
      feats, w_qkv, nullptr, q, k, v, 4096, 768, 256, 256, 768);

  gemm_kernel<false><<<dim3(256, 2), dim3(256), 0, stream>>>(
      q, w_e1, b_e1, qe, nullptr, nullptr, 16384, 128, 64, 64, 128);
  gemm_kernel<false><<<dim3(256, 2), dim3(256), 0, stream>>>(
      k, w_e1, nullptr, ke, nullptr, nullptr, 16384, 128, 64, 64, 128);

  constexpr int FUSED_SMEM = 39216 * 4;   // 156,864 B dynamic LDS
  (void)hipFuncSetAttribute(reinterpret_cast<const void*>(fused_kernel),
                            hipFuncAttributeMaxDynamicSharedMemorySize, FUSED_SMEM);
  fused_kernel<<<dim3(NODES), dim3(512), FUSED_SMEM, stream>>>(
      idx, dnb, reln, qe, ke, v,
      w_p1, b_p1, w_p2, b_p2, w_e1, w_e2, b_e2,
      w_a1, b_a1, w_a2, b_a2, w_c1, b_c1, w_c2, b_c2,
      hsum, outC);

  gemm_kernel<false><<<dim3(64, 4), dim3(256), 0, stream>>>(
      hsum, w_out, b_out, outF, nullptr, nullptr, 4096, 256, 256, 256, 256);
}

// Round 7
// 745.562 us; speedup vs baseline: 1.4594x; 1.4594x over previous
//
#include <hip/hip_runtime.h>
#include <float.h>
#include <math.h>

#define BB   2
#define NPTS 2048
#define NODES (BB*NPTS)   // 4096
#define NNB  32
#define NH   4
#define NDH  64

// padded LDS row strides (== 4 mod 32 words -> conflict-free broadcast groups)
#define SCR_LD  132
#define POS_LD   68
#define POSE_LD 132
#define M_LD     68
#define E2T_LD  132

// ======================= KNN (exact numpy replication) =======================
__global__ __launch_bounds__(256) void knn_kernel(const float* __restrict__ coors,
    int* __restrict__ idx_out, float* __restrict__ dnb_out, float* __restrict__ rel_out) {
#pragma clang fp contract(off)
  const int node = blockIdx.x;
  const int b = node >> 11;
  const int i = node & (NPTS - 1);
  __shared__ float cx[NPTS], cy[NPTS], cz[NPTS];
  __shared__ float wdist[4]; __shared__ int wjj[4];
  __shared__ float win_d_s; __shared__ int win_j_s;
  __shared__ float sel_d[NNB]; __shared__ int sel_j[NNB];
  const float* cb = coors + (size_t)b * NPTS * 3;
  for (int j = threadIdx.x; j < NPTS; j += 256) {
    cx[j] = cb[3*j]; cy[j] = cb[3*j+1]; cz[j] = cb[3*j+2];
  }
  __syncthreads();
  const float xi = cx[i], yi = cy[i], zi = cz[i];
  float dl[8]; int jl[8];
  #pragma unroll
  for (int s = 0; s < 8; ++s) {
    int j = threadIdx.x + (s << 8);
    float dx = xi - cx[j];
    float dy = yi - cy[j];
    float dz = zi - cz[j];
    float ss = dx*dx + dy*dy;   // contract(off): matches numpy rounding
    ss = ss + dz*dz;
    dl[s] = sqrtf(ss);          // correctly rounded by default on HIP
    jl[s] = j;
  }
  for (int it = 0; it < NNB; ++it) {
    float bd = FLT_MAX; int bj = 0x7FFFFFFF;
    #pragma unroll
    for (int s = 0; s < 8; ++s)
      if (dl[s] < bd || (dl[s] == bd && jl[s] < bj)) { bd = dl[s]; bj = jl[s]; }
    #pragma unroll
    for (int off = 32; off > 0; off >>= 1) {
      float od = __shfl_down(bd, off, 64);
      int   oj = __shfl_down(bj, off, 64);
      if (od < bd || (od == bd && oj < bj)) { bd = od; bj = oj; }
    }
    if ((threadIdx.x & 63) == 0) { wdist[threadIdx.x >> 6] = bd; wjj[threadIdx.x >> 6] = bj; }
    __syncthreads();
    if (threadIdx.x == 0) {
      float fd = wdist[0]; int fj = wjj[0];
      #pragma unroll
      for (int w = 1; w < 4; ++w)
        if (wdist[w] < fd || (wdist[w] == fd && wjj[w] < fj)) { fd = wdist[w]; fj = wjj[w]; }
      win_d_s = fd; win_j_s = fj; sel_d[it] = fd; sel_j[it] = fj;
    }
    __syncthreads();
    const int wj = win_j_s;
    #pragma unroll
    for (int s = 0; s < 8; ++s) if (jl[s] == wj) dl[s] = FLT_MAX;
    __syncthreads();
  }
  if (threadIdx.x < NNB) {
    int s = threadIdx.x;
    int j = sel_j[s];
    idx_out[(size_t)node*NNB + s] = j;
    dnb_out[(size_t)node*NNB + s] = sel_d[s];
    float* rp = rel_out + ((size_t)node*NNB + s)*3;
    rp[0] = xi - cx[j]; rp[1] = yi - cy[j]; rp[2] = zi - cz[j];
  }
}

// ======================= generic f32 GEMM (64x64 tile) =======================
template<bool SPLIT>
__global__ __launch_bounds__(256) void gemm_kernel(const float* __restrict__ A,
    const float* __restrict__ Bm, const float* __restrict__ bias,
    float* __restrict__ C0, float* __restrict__ C1, float* __restrict__ C2,
    int Mn, int Nn, int Kn, int lda, int ldb) {
  __shared__ float As[64][17];
  __shared__ __align__(16) float Bs[16][64];
  const int bm = blockIdx.x * 64, bn = blockIdx.y * 64;
  const int tx = threadIdx.x & 15, ty = threadIdx.x >> 4;
  const int lm = threadIdx.x >> 2, lk = (threadIdx.x & 3) * 4;
  const int br = threadIdx.x >> 4, bc = (threadIdx.x & 15) * 4;
  float acc[4][4] = {};
  for (int k0 = 0; k0 < Kn; k0 += 16) {
    float4 av = *(const float4*)(A + (size_t)(bm + lm)*lda + k0 + lk);
    As[lm][lk+0] = av.x; As[lm][lk+1] = av.y; As[lm][lk+2] = av.z; As[lm][lk+3] = av.w;
    float4 bv = *(const float4*)(Bm + (size_t)(k0 + br)*ldb + bn + bc);
    *(float4*)&Bs[br][bc] = bv;
    __syncthreads();
    #pragma unroll
    for (int kk = 0; kk < 16; ++kk) {
      float a0 = As[ty*4+0][kk], a1 = As[ty*4+1][kk], a2 = As[ty*4+2][kk], a3 = As[ty*4+3][kk];
      float4 bq = *(const float4*)&Bs[kk][tx*4];
      acc[0][0] += a0*bq.x; acc[0][1] += a0*bq.y; acc[0][2] += a0*bq.z; acc[0][3] += a0*bq.w;
      acc[1][0] += a1*bq.x; acc[1][1] += a1*bq.y; acc[1][2] += a1*bq.z; acc[1][3] += a1*bq.w;
      acc[2][0] += a2*bq.x; acc[2][1] += a2*bq.y; acc[2][2] += a2*bq.z; acc[2][3] += a2*bq.w;
      acc[3][0] += a3*bq.x; acc[3][1] += a3*bq.y; acc[3][2] += a3*bq.z; acc[3][3] += a3*bq.w;
    }
    __syncthreads();
  }
  #pragma unroll
  for (int r = 0; r < 4; ++r) {
    #pragma unroll
    for (int c = 0; c < 4; ++c) {
      int row = bm + ty*4 + r, col = bn + tx*4 + c;
      float vv = acc[r][c];
      if (bias) vv += bias[col];
      if (SPLIT) {
        int w = col >> 8, cc = col & 255;
        float* Cp = (w == 0) ? C0 : ((w == 1) ? C1 : C2);
        Cp[(size_t)row*256 + cc] = vv;
      } else {
        C0[(size_t)row*Nn + col] = vv;
      }
    }
  }
}

// ======================= fused per-node kernel =======================
// block = one node, 512 threads. 77,248 B dynamic LDS -> 2 blocks/CU.
// w_p2 / w_e1 / w_c1 read directly from global (L1/L2-resident).
__global__ __launch_bounds__(512, 4) void fused_kernel(
    const int* __restrict__ idx, const float* __restrict__ dnb, const float* __restrict__ relnb,
    const float* __restrict__ qe, const float* __restrict__ ke, const float* __restrict__ v,
    const float* __restrict__ w_p1, const float* __restrict__ b_p1,
    const float* __restrict__ w_p2, const float* __restrict__ b_p2,
    const float* __restrict__ w_e1, const float* __restrict__ w_e2, const float* __restrict__ b_e2,
    const float* __restrict__ w_a1, const float* __restrict__ b_a1,
    const float* __restrict__ w_a2, const float* __restrict__ b_a2,
    const float* __restrict__ w_c1, const float* __restrict__ b_c1,
    const float* __restrict__ w_c2, const float* __restrict__ b_c2,
    float* __restrict__ hsum, float* __restrict__ coors_out) {
  extern __shared__ float sm[];
  float* w_p1s = sm;               // 1152
  float* b_p1s = w_p1s + 1152;     // 128
  float* b_p2s = b_p1s + 128;      // 64
  float* w_e2Ts= b_p2s + 64;       // 16*132 = 2112 (transposed)
  float* b_e2s = w_e2Ts + 2112;    // 16
  float* w_a1s = b_e2s + 16;       // 1024
  float* b_a1s = w_a1s + 1024;     // 64
  float* w_a2s = b_a1s + 64;       // 64
  float* b_c1s = w_a2s + 64;       // 64
  float* w_c2s = b_c1s + 64;       // 64
  float* qe_s  = w_c2s + 64;       // 512
  float* fe_s  = qe_s + 512;       // 288
  float* pos_s = fe_s + 288;       // 32*68  = 2176
  float* pose_s= pos_s + 2176;     // 32*132 = 4224
  float* scr   = pose_s + 4224;    // 32*132 = 4224 (ph / h1e / ch)
  float* m_all = scr + 4224;       // 32*68  = 2176
  float* sim_s = m_all + 2176;     // 128
  float* attn_s= sim_s + 128;      // 128
  float* part_s= attn_s + 128;     // 512
  float* cw_s  = part_s + 512;     // 32
  float* dnb_s = cw_s + 32;        // 32
  float* rel_s = dnb_s + 32;       // 96
  int*   idx_s = (int*)(rel_s + 96); // 32   -> total 19312 floats = 77248 B
  const int t = threadIdx.x;
  const int node = blockIdx.x;
  const int b = node >> 11;

  // ---- stage small weights + per-node data ----
  for (int i = t; i < 1152; i += 512) w_p1s[i] = w_p1[i];
  for (int i = t; i < 2048; i += 512) {            // transpose w_e2 [128][16] -> [16][132]
    int kx = i >> 4, mt = i & 15;
    w_e2Ts[mt*E2T_LD + kx] = w_e2[i];
  }
  for (int i = t; i < 1024; i += 512) w_a1s[i] = w_a1[i];
  if (t < 128) b_p1s[t] = b_p1[t];
  if (t >= 128 && t < 192) b_p2s[t-128] = b_p2[t-128];
  if (t >= 192 && t < 208) b_e2s[t-192] = b_e2[t-192];
  if (t >= 256 && t < 320) b_a1s[t-256] = b_a1[t-256];
  if (t >= 320 && t < 384) w_a2s[t-320] = w_a2[t-320];
  if (t >= 384 && t < 448) b_c1s[t-384] = b_c1[t-384];
  if (t >= 448 && t < 512) w_c2s[t-448] = w_c2[t-448];
  qe_s[t] = qe[(size_t)node*512 + t];
  if (t < NNB) { idx_s[t] = idx[(size_t)node*NNB + t]; dnb_s[t] = dnb[(size_t)node*NNB + t]; }
  if (t < NNB*3) rel_s[t] = relnb[(size_t)node*NNB*3 + t];
  __syncthreads();

  // ---- P1a: fourier features fe[32][9] ----
  if (t < NNB) {
    float d = dnb_s[t];
    float* f = fe_s + t*9;
    f[0] = sinf(d);          f[1] = sinf(d*0.5f);
    f[2] = sinf(d*0.25f);    f[3] = sinf(d*0.125f);
    f[4] = cosf(d);          f[5] = cosf(d*0.5f);
    f[6] = cosf(d*0.25f);    f[7] = cosf(d*0.125f);
    f[8] = d;
  }
  __syncthreads();

  // ---- P1b: ph = relu(fe @ w_p1 + b_p1) -> scr[j][o] ----
  #pragma unroll
  for (int rep = 0; rep < 8; ++rep) {
    int i2 = t + rep*512;
    int j = i2 >> 7, o = i2 & 127;
    const float* f = fe_s + j*9;
    float acc = b_p1s[o];
    #pragma unroll
    for (int r = 0; r < 9; ++r) acc += f[r] * w_p1s[r*128 + o];
    scr[j*SCR_LD + o] = fmaxf(acc, 0.0f);
  }
  __syncthreads();

  // ---- P1c: pos = ph @ w_p2 + b_p2 -> pos_s ; w_p2 from global ----
  {
    int j = t >> 4, og = (t & 15) * 4;
    const float* ph = scr + j*SCR_LD;
    float s0=0,s1=0,s2=0,s3=0, u0=0,u1=0,u2=0,u3=0;
    #pragma unroll 8
    for (int kx = 0; kx < 128; kx += 2) {
      float p0 = ph[kx], p1 = ph[kx+1];
      float4 w0 = *(const float4*)(w_p2 + kx*64 + og);
      float4 w1 = *(const float4*)(w_p2 + (kx+1)*64 + og);
      s0 += p0*w0.x; s1 += p0*w0.y; s2 += p0*w0.z; s3 += p0*w0.w;
      u0 += p1*w1.x; u1 += p1*w1.y; u2 += p1*w1.z; u3 += p1*w1.w;
    }
    pos_s[j*POS_LD+og+0] = b_p2s[og+0] + (s0+u0);
    pos_s[j*POS_LD+og+1] = b_p2s[og+1] + (s1+u1);
    pos_s[j*POS_LD+og+2] = b_p2s[og+2] + (s2+u2);
    pos_s[j*POS_LD+og+3] = b_p2s[og+3] + (s3+u3);
  }
  __syncthreads();

  // ---- P2: pose = pos @ w_e1 -> pose_s ; w_e1 from global ----
  #pragma unroll
  for (int rep = 0; rep < 2; ++rep) {
    int i2 = t + rep*512;
    int j = i2 >> 5, og = (i2 & 31) * 4;
    const float* pj = pos_s + j*POS_LD;
    float s0=0,s1=0,s2=0,s3=0, u0=0,u1=0,u2=0,u3=0;
    #pragma unroll 8
    for (int kx = 0; kx < 64; kx += 2) {
      float p0 = pj[kx], p1 = pj[kx+1];
      float4 w0 = *(const float4*)(w_e1 + kx*128 + og);
      float4 w1 = *(const float4*)(w_e1 + (kx+1)*128 + og);
      s0 += p0*w0.x; s1 += p0*w0.y; s2 += p0*w0.z; s3 += p0*w0.w;
      u0 += p1*w1.x; u1 += p1*w1.y; u2 += p1*w1.z; u3 += p1*w1.w;
    }
    pose_s[j*POSE_LD+og+0] = s0+u0;
    pose_s[j*POSE_LD+og+1] = s1+u1;
    pose_s[j*POSE_LD+og+2] = s2+u2;
    pose_s[j*POSE_LD+og+3] = s3+u3;
  }
  __syncthreads();

  // ---- P3: per head: h1e = relu(qe - ke + pose) ; m = relu(h1e @ w_e2 + b_e2)
  //      GEMV full-width: one output (j, mt) per thread.
  for (int h = 0; h < NH; ++h) {
    #pragma unroll
    for (int rep = 0; rep < 8; ++rep) {
      int i2 = t + rep*512;
      int j = i2 >> 7, o = i2 & 127;
      float kv = ke[((size_t)((b << 11) + idx_s[j])*NH + h)*128 + o];
      scr[j*SCR_LD + o] = fmaxf(qe_s[h*128+o] - kv + pose_s[j*POSE_LD + o], 0.0f);
    }
    __syncthreads();
    {
      int j = t >> 4, mt = t & 15;
      const float* hp = scr + j*SCR_LD;
      const float* wt = w_e2Ts + mt*E2T_LD;
      float s0=0,s1=0,s2=0,s3=0;
      #pragma unroll 8
      for (int kx = 0; kx < 128; kx += 4) {
        float4 hv = *(const float4*)(hp + kx);
        float4 wv = *(const float4*)(wt + kx);
        s0 += hv.x*wv.x; s1 += hv.y*wv.y; s2 += hv.z*wv.z; s3 += hv.w*wv.w;
      }
      m_all[j*M_LD + h*16 + mt] = fmaxf(b_e2s[mt] + ((s0+s1)+(s2+s3)), 0.0f);
    }
    __syncthreads();
  }

  // ---- P4a: sim = relu(m @ w_a1 + b_a1) @ w_a2 + b_a2 ----
  {
    int j = t >> 4, h = (t >> 2) & 3, qq = t & 3;
    float mreg[16];
    #pragma unroll
    for (int mt = 0; mt < 16; ++mt) mreg[mt] = m_all[j*M_LD + h*16 + mt];
    float acc = 0.0f;
    #pragma unroll
    for (int oi = 0; oi < 16; ++oi) {
      int oo = qq*16 + oi;
      float ah = b_a1s[oo];
      #pragma unroll
      for (int mt = 0; mt < 16; ++mt) ah += mreg[mt] * w_a1s[mt*64 + oo];
      acc += fmaxf(ah, 0.0f) * w_a2s[oo];
    }
    part_s[t] = acc;
  }
  __syncthreads();
  if (t < 128) {
    int j = t >> 2, h = t & 3;
    const float* pp = part_s + j*16 + h*4;
    sim_s[h*32 + j] = ((pp[0]+pp[1]) + (pp[2]+pp[3])) + b_a2[0];
  }
  __syncthreads();
  if (t < 4) {   // softmax over j, faithful to reference
    const float* sp = sim_s + t*32;
    float mx = sp[0];
    for (int j = 1; j < 32; ++j) mx = fmaxf(mx, sp[j]);
    float s = 0.0f; float* ap = attn_s + t*32;
    for (int j = 0; j < 32; ++j) { float e = expf(sp[j] - mx); ap[j] = e; s += e; }
    for (int j = 0; j < 32; ++j) ap[j] = ap[j] / s;
  }
  __syncthreads();

  // ---- P5a: attention output, full width: (jhalf, h, dd) per thread ----
  {
    int jh = t >> 8, h = (t >> 6) & 3, dd = t & 63;
    float acc = 0.0f;
    #pragma unroll
    for (int jj = 0; jj < 16; ++jj) {
      int j = jh*16 + jj;
      float vv = v[(size_t)((b << 11) + idx_s[j])*256 + h*64 + dd] + pos_s[j*POS_LD + dd];
      acc += attn_s[h*32 + j] * vv;
    }
    part_s[t] = acc;
  }
  __syncthreads();
  if (t < 256) hsum[(size_t)node*256 + t] = part_s[t] + part_s[t + 256];
  __syncthreads();

  // ---- P4b: coor MLP: ch = relu(m_all @ w_c1 + b_c1) ; w_c1 from global ----
  {
    int j = t >> 4, og = (t & 15) * 4;
    const float* mj = m_all + j*M_LD;
    float s0=0,s1=0,s2=0,s3=0, u0=0,u1=0,u2=0,u3=0;
    #pragma unroll 8
    for (int kx = 0; kx < 64; kx += 2) {
      float m0 = mj[kx], m1 = mj[kx+1];
      float4 w0 = *(const float4*)(w_c1 + kx*64 + og);
      float4 w1 = *(const float4*)(w_c1 + (kx+1)*64 + og);
      s0 += m0*w0.x; s1 += m0*w0.y; s2 += m0*w0.z; s3 += m0*w0.w;
      u0 += m1*w1.x; u1 += m1*w1.y; u2 += m1*w1.z; u3 += m1*w1.w;
    }
    scr[j*SCR_LD+og+0] = fmaxf(b_c1s[og+0] + (s0+u0), 0.0f);
    scr[j*SCR_LD+og+1] = fmaxf(b_c1s[og+1] + (s1+u1), 0.0f);
    scr[j*SCR_LD+og+2] = fmaxf(b_c1s[og+2] + (s2+u2), 0.0f);
    scr[j*SCR_LD+og+3] = fmaxf(b_c1s[og+3] + (s3+u3), 0.0f);
  }
  __syncthreads();
  if (t < 128) {
    int j = t >> 2, qq = t & 3;
    const float* cj = scr + j*SCR_LD + qq*16;
    const float* wc = w_c2s + qq*16;
    float acc = 0.0f;
    #pragma unroll
    for (int oo = 0; oo < 16; ++oo) acc += cj[oo] * wc[oo];
    part_s[t] = acc;
  }
  __syncthreads();
  if (t < 32) {
    const float* pp = part_s + t*4;
    cw_s[t] = ((pp[0]+pp[1]) + (pp[2]+pp[3])) + b_c2[0];
  }
  __syncthreads();
  if (t < 3) {
    float acc = 0.0f;
    for (int j = 0; j < 32; ++j) acc += cw_s[j] * rel_s[j*3 + t];
    coors_out[(size_t)node*3 + t] = acc;
  }
}

// ======================= launch =======================
extern "C" void kernel_launch(void* const* d_in, const int* in_sizes, int n_in,
                              void* d_out, int out_size, void* d_ws, size_t ws_size,
                              hipStream_t stream) {
  const float* feats = (const float*)d_in[0];
  const float* coors = (const float*)d_in[1];
  const float* w_qkv = (const float*)d_in[2];
  const float* w_out = (const float*)d_in[3];
  const float* b_out = (const float*)d_in[4];
  const float* w_p1  = (const float*)d_in[5];
  const float* b_p1  = (const float*)d_in[6];
  const float* w_p2  = (const float*)d_in[7];
  const float* b_p2  = (const float*)d_in[8];
  const float* w_e1  = (const float*)d_in[9];
  const float* b_e1  = (const float*)d_in[10];
  const float* w_e2  = (const float*)d_in[11];
  const float* b_e2  = (const float*)d_in[12];
  const float* w_a1  = (const float*)d_in[13];
  const float* b_a1  = (const float*)d_in[14];
  const float* w_a2  = (const float*)d_in[15];
  const float* b_a2  = (const float*)d_in[16];
  const float* w_c1  = (const float*)d_in[17];
  const float* b_c1  = (const float*)d_in[18];
  const float* w_c2  = (const float*)d_in[19];
  const float* b_c2  = (const float*)d_in[20];

  float* ws   = (float*)d_ws;
  float* q    = ws;                 // 4096*256
  float* k    = q   + 1048576;
  float* v    = k   + 1048576;
  float* qe   = v   + 1048576;      // 16384*128 (incl. +b_e1)
  float* ke   = qe  + 2097152;
  float* hsum = ke  + 2097152;      // 4096*256
  int*   idx  = (int*)(hsum + 1048576);   // 4096*32
  float* dnb  = (float*)(idx + 131072);
  float* reln = dnb + 131072;       // 4096*32*3

  float* outF = (float*)d_out;              // (B,N,256)
  float* outC = outF + (size_t)NODES*256;   // (B,N,3)

  knn_kernel<<<dim3(NODES), dim3(256), 0, stream>>>(coors, idx, dnb, reln);

  gemm_kernel<true><<<dim3(64, 12), dim3(256), 0, stream>>>(
      feats, w_qkv, nullptr, q, k, v, 4096, 768, 256, 256, 768);

  gemm_kernel<false><<<dim3(256, 2), dim3(256), 0, stream>>>(
      q, w_e1, b_e1, qe, nullptr, nullptr, 16384, 128, 64, 64, 128);
  gemm_kernel<false><<<dim3(256, 2), dim3(256), 0, stream>>>(
      k, w_e1, nullptr, ke, nullptr, nullptr, 16384, 128, 64, 64, 128);

  constexpr int FUSED_SMEM = 19312 * 4;   // 77,248 B dynamic LDS -> 2 blocks/CU
  (void)hipFuncSetAttribute(reinterpret_cast<const void*>(fused_kernel),
                            hipFuncAttributeMaxDynamicSharedMemorySize, FUSED_SMEM);
  fused_kernel<<<dim3(NODES), dim3(512), FUSED_SMEM, stream>>>(
      idx, dnb, reln, qe, ke, v,
      w_p1, b_p1, w_p2, b_p2, w_e1, w_e2, b_e2,
      w_a1, b_a1, w_a2, b_a2, w_c1, b_c1, w_c2, b_c2,
      hsum, outC);

  gemm_kernel<false><<<dim3(64, 4), dim3(256), 0, stream>>>(
      hsum, w_out, b_out, outF, nullptr, nullptr, 4096, 256, 256, 256, 256);
}